// Round 10
// baseline (651.963 us; speedup 1.0000x reference)
//
#include <hip/hip_runtime.h>
#include <hip/hip_bf16.h>

// LSTM: B=16384, T=200, IN=9, H=64, OUT=3, 2 layers + linear head.
// Round 10: dual-tile retry, register-lean (R9 spilled: WRITE_SIZE 30MB).
//   Block = 32 batches = 2 independent 16-batch tiles (P,Q) sharing the
//   112-reg weight set. One barrier/step serves both tiles; tile Q's MFMA
//   cluster overlaps tile P's transcendental cell chain (ILP within wave).
//   Changes vs R9: no LDS x-window (direct per-lane prefetch, R7 style),
//   P-then-Q sequencing (one D live), no setprio, literal-parity lambda.
// 256 threads (4 waves). Wave w owns gate n-tiles {w, w+4, w+8, w+12}.
// Fragment layouts (gfx950 16x16x32, verified R2-R9):
//   A: lane l holds A[m=l&15][k=4*(l>>4)+(j&3)+16*(j>>2)]
//   B: lane l holds B[k=...][n=l&15]
//   C/D: col=l&15, row=(l>>4)*4+reg
// LDS h-state k-PERMUTED (R3). Weight pre-scale (R7): i,f,o x(-log2e), g x(-2log2e).
// cell math (R8): merged-reciprocal + batched 4-way rcp.

#define B_TOT   16384
#define T_STEPS 200
#define IN_DIM  9
#define HDIM    64

#define PK1_OFF 0         // [3][16][64][8] = 24576 f16
#define PK2_OFF 24576     // [4][16][64][8] = 32768 f16
#define BSUM_HALF_OFF 57344   // then 512 f32 (b1[256], b2[256])
#define PACK_W_TOT 57344
#define PACK_TOT (PACK_W_TOT + 512)

#define L2E     1.44269504089f
#define TWOL2E  2.88539008178f

typedef _Float16 half8  __attribute__((ext_vector_type(8)));
typedef float    f32x4  __attribute__((ext_vector_type(4)));
typedef float    f4u    __attribute__((ext_vector_type(4), aligned(4)));

// ---------------- prep: repack weights (B-frag layout, scales folded) -------
__global__ void pack_kernel(const float* __restrict__ Wih1, const float* __restrict__ Whh1,
                            const float* __restrict__ bih1, const float* __restrict__ bhh1,
                            const float* __restrict__ Wih2, const float* __restrict__ Whh2,
                            const float* __restrict__ bih2, const float* __restrict__ bhh2,
                            float* __restrict__ ws) {
    int e = blockIdx.x * 256 + threadIdx.x;
    if (e >= PACK_TOT) return;
    _Float16* wh = (_Float16*)ws;
    float* bptr = (float*)(wh + BSUM_HALF_OFF);
    auto gscale = [](int q) -> float {
        int gt = q >> 6;                       // 0=i,1=f,2=g,3=o
        return (gt == 2) ? (-2.0f * L2E) : -L2E;
    };
    if (e < PK2_OFF) {
        int j = e & 7, lane = (e >> 3) & 63, nt = (e >> 9) & 15, c = e >> 13;
        int k = c * 32 + 4 * (lane >> 4) + (j & 3) + 16 * (j >> 2);
        int q = nt * 16 + (lane & 15);
        float v = 0.0f;
        if (k < 64)      v = Whh1[q * 64 + k];
        else if (k < 73) v = Wih1[q * 9 + (k - 64)];
        wh[e] = (_Float16)(v * gscale(q));
    } else if (e < PACK_W_TOT) {
        int e2 = e - PK2_OFF;
        int j = e2 & 7, lane = (e2 >> 3) & 63, nt = (e2 >> 9) & 15, c = e2 >> 13;
        int k = c * 32 + 4 * (lane >> 4) + (j & 3) + 16 * (j >> 2);
        int q = nt * 16 + (lane & 15);
        float v = (k < 64) ? Wih2[q * 64 + k] : Whh2[q * 64 + (k - 64)];
        wh[e] = (_Float16)(v * gscale(q));
    } else if (e < PACK_W_TOT + 256) {
        int q = e - PACK_W_TOT;
        bptr[q] = (bih1[q] + bhh1[q]) * gscale(q);
    } else {
        int q = e - PACK_W_TOT - 256;
        bptr[256 + q] = (bih2[q] + bhh2[q]) * gscale(q);
    }
}

// ---------------- main sequential LSTM ----------------
__global__ __launch_bounds__(256, 2) void lstm_mfma(
    const float* __restrict__ x,
    const float* __restrict__ ws_f,
    const float* __restrict__ Wout,
    const float* __restrict__ bout,
    float* __restrict__ out)
{
    const int tid  = threadIdx.x;
    const int lane = tid & 63;
    const int w    = __builtin_amdgcn_readfirstlane(tid >> 6);   // 0..3
    const int l15  = lane & 15;
    const int l4   = lane >> 4;

    const _Float16* wh  = (const _Float16*)ws_f;
    const _Float16* pk1 = wh + PK1_OFF;
    const _Float16* pk2 = wh + PK2_OFF;
    const float* bsum   = (const float*)(wh + BSUM_HALF_OFF);

    __shared__ _Float16 h1P[2][16][72], h2P[2][16][72];
    __shared__ _Float16 h1Q[2][16][72], h2Q[2][16][72];

    for (int i = tid; i < 2 * 16 * 72; i += 256) {
        (&h1P[0][0][0])[i] = (_Float16)0.0f; (&h2P[0][0][0])[i] = (_Float16)0.0f;
        (&h1Q[0][0][0])[i] = (_Float16)0.0f; (&h2Q[0][0][0])[i] = (_Float16)0.0f;
    }

    const int bbase = blockIdx.x * 32;
    const float* xbP = x + (long)(bbase + l15) * (T_STEPS * IN_DIM);
    const float* xbQ = x + (long)(bbase + 16 + l15) * (T_STEPS * IN_DIM);

    // per-tile x prefetch regs (1 step ahead); l4==3 lanes stay zero
    f4u  cxP = {0.f,0.f,0.f,0.f}, cxQ = {0.f,0.f,0.f,0.f};
    float cx8P = 0.0f, cx8Q = 0.0f;
    auto prefetch_tile = [&](const float* xb, f4u& cx, float& cx8, int tt) {
        const float* xp = xb + tt * IN_DIM;
        if (l4 < 2)       cx  = *(const f4u*)(xp + 4 * l4);
        else if (l4 == 2) cx8 = xp[8];
    };
    auto build_ax2 = [&](const f4u& cx, float cx8) -> half8 {
        half8 ax;
        float e0 = (l4 == 2) ? cx8 : cx[0];
        ax[0] = (_Float16)e0;    ax[1] = (_Float16)cx[1];
        ax[2] = (_Float16)cx[2]; ax[3] = (_Float16)cx[3];
        ax[4] = ax[5] = ax[6] = ax[7] = (_Float16)0.0f;
        return ax;
    };

    // ---- weight B-fragments: 28 x half8, loop-pinned, shared by both tiles
    half8 bw1_00, bw1_01, bw1_02, bw1_03;
    half8 bw1_10, bw1_11, bw1_12, bw1_13;
    half8 bw1_20, bw1_21, bw1_22, bw1_23;
    half8 bw2_00, bw2_01, bw2_02, bw2_03;
    half8 bw2_10, bw2_11, bw2_12, bw2_13;
    half8 bw2_20, bw2_21, bw2_22, bw2_23;
    half8 bw2_30, bw2_31, bw2_32, bw2_33;
    {
        #define LD1(c,g) *(const half8*)(pk1 + (((c * 16) + (w + 4 * g)) * 64 + lane) * 8)
        #define LD2(c,g) *(const half8*)(pk2 + (((c * 16) + (w + 4 * g)) * 64 + lane) * 8)
        bw1_00 = LD1(0,0); bw1_01 = LD1(0,1); bw1_02 = LD1(0,2); bw1_03 = LD1(0,3);
        bw1_10 = LD1(1,0); bw1_11 = LD1(1,1); bw1_12 = LD1(1,2); bw1_13 = LD1(1,3);
        bw1_20 = LD1(2,0); bw1_21 = LD1(2,1); bw1_22 = LD1(2,2); bw1_23 = LD1(2,3);
        bw2_00 = LD2(0,0); bw2_01 = LD2(0,1); bw2_02 = LD2(0,2); bw2_03 = LD2(0,3);
        bw2_10 = LD2(1,0); bw2_11 = LD2(1,1); bw2_12 = LD2(1,2); bw2_13 = LD2(1,3);
        bw2_20 = LD2(2,0); bw2_21 = LD2(2,1); bw2_22 = LD2(2,2); bw2_23 = LD2(2,3);
        bw2_30 = LD2(3,0); bw2_31 = LD2(3,1); bw2_32 = LD2(3,2); bw2_33 = LD2(3,3);
        #undef LD1
        #undef LD2
    }

    float bias1[4], bias2[4];
    #pragma unroll
    for (int g = 0; g < 4; ++g) {
        bias1[g] = bsum[(w + 4 * g) * 16 + l15];
        bias2[g] = bsum[256 + (w + 4 * g) * 16 + l15];
    }

    const int hpos = ((w >> 1) << 5) + 8 * (l15 >> 2) + (l15 & 3) + ((w & 1) << 2);

    f32x4 c1P = {0.f,0.f,0.f,0.f}, c2P = {0.f,0.f,0.f,0.f};
    f32x4 c1Q = {0.f,0.f,0.f,0.f}, c2Q = {0.f,0.f,0.f,0.f};

    // merged cell update (R8): batched 4-way reciprocals
    auto cell_update = [&](f32x4* G, f32x4& cs, _Float16* hb) {
        float num[4], den[4], eo4[4], d2[4], hs4[4];
        #pragma unroll
        for (int r = 0; r < 4; ++r) {
            float ei = __builtin_amdgcn_exp2f(G[0][r]);
            float ef = __builtin_amdgcn_exp2f(G[1][r]);
            float eg = __builtin_amdgcn_exp2f(G[2][r]);
            eo4[r]   = __builtin_amdgcn_exp2f(G[3][r]);
            float ai = 1.0f + ei, af = 1.0f + ef, ag = 1.0f + eg;
            float gm = 1.0f - eg;
            float pp = ai * ag;
            num[r] = __builtin_fmaf(gm, af, cs[r] * pp);
            den[r] = af * pp;
        }
        float s01 = den[0] * den[1], s23 = den[2] * den[3];
        float Pinv = __builtin_amdgcn_rcpf(s01 * s23);
        float r01 = Pinv * s23, r23 = Pinv * s01;
        float inv[4] = {r01 * den[1], r01 * den[0], r23 * den[3], r23 * den[2]};
        #pragma unroll
        for (int r = 0; r < 4; ++r) {
            float cc = num[r] * inv[r];
            cs[r] = cc;
            float z  = cc * TWOL2E;
            int   zi = __float_as_int(z);
            float ec = __builtin_amdgcn_exp2f(__int_as_float(zi | (int)0x80000000));
            float tm = 1.0f - ec;
            d2[r] = (1.0f + eo4[r]) * (1.0f + ec);
            hs4[r] = __int_as_float(__float_as_int(tm) ^ (zi & (int)0x80000000));
        }
        float t01 = d2[0] * d2[1], t23 = d2[2] * d2[3];
        float Qinv = __builtin_amdgcn_rcpf(t01 * t23);
        float q01 = Qinv * t23, q23 = Qinv * t01;
        float jnv[4] = {q01 * d2[1], q01 * d2[0], q23 * d2[3], q23 * d2[2]};
        #pragma unroll
        for (int r = 0; r < 4; ++r)
            hb[(4 * l4 + r) * 72 + hpos] = (_Float16)(hs4[r] * jnv[r]);
    };

    auto initb = [&](f32x4* A, const float* b) {
        #pragma unroll
        for (int g = 0; g < 4; ++g) A[g] = (f32x4){b[g], b[g], b[g], b[g]};
    };

    // post-barrier per-tile phase: D=gates2(t), Cacc=gates1(t+1), cell2.
    // Pointers passed with literal parity -> compile-time LDS offsets.
    auto tile_phase = [&](f32x4* Cacc, f32x4& cs2,
                          const _Float16* h1w, const _Float16* h2r,
                          _Float16* h2w, half8 axn) {
        half8 u0 = *(const half8*)(h1w + l15 * 72 +  0 + 8 * l4);
        half8 u1 = *(const half8*)(h1w + l15 * 72 + 32 + 8 * l4);
        half8 v0 = *(const half8*)(h2r + l15 * 72 +  0 + 8 * l4);
        half8 v1 = *(const half8*)(h2r + l15 * 72 + 32 + 8 * l4);
        f32x4 D[4]; initb(D, bias2);
        D[0] = __builtin_amdgcn_mfma_f32_16x16x32_f16(u0, bw2_00, D[0], 0, 0, 0);
        D[1] = __builtin_amdgcn_mfma_f32_16x16x32_f16(u0, bw2_01, D[1], 0, 0, 0);
        D[2] = __builtin_amdgcn_mfma_f32_16x16x32_f16(u0, bw2_02, D[2], 0, 0, 0);
        D[3] = __builtin_amdgcn_mfma_f32_16x16x32_f16(u0, bw2_03, D[3], 0, 0, 0);
        D[0] = __builtin_amdgcn_mfma_f32_16x16x32_f16(u1, bw2_10, D[0], 0, 0, 0);
        D[1] = __builtin_amdgcn_mfma_f32_16x16x32_f16(u1, bw2_11, D[1], 0, 0, 0);
        D[2] = __builtin_amdgcn_mfma_f32_16x16x32_f16(u1, bw2_12, D[2], 0, 0, 0);
        D[3] = __builtin_amdgcn_mfma_f32_16x16x32_f16(u1, bw2_13, D[3], 0, 0, 0);
        D[0] = __builtin_amdgcn_mfma_f32_16x16x32_f16(v0, bw2_20, D[0], 0, 0, 0);
        D[1] = __builtin_amdgcn_mfma_f32_16x16x32_f16(v0, bw2_21, D[1], 0, 0, 0);
        D[2] = __builtin_amdgcn_mfma_f32_16x16x32_f16(v0, bw2_22, D[2], 0, 0, 0);
        D[3] = __builtin_amdgcn_mfma_f32_16x16x32_f16(v0, bw2_23, D[3], 0, 0, 0);
        D[0] = __builtin_amdgcn_mfma_f32_16x16x32_f16(v1, bw2_30, D[0], 0, 0, 0);
        D[1] = __builtin_amdgcn_mfma_f32_16x16x32_f16(v1, bw2_31, D[1], 0, 0, 0);
        D[2] = __builtin_amdgcn_mfma_f32_16x16x32_f16(v1, bw2_32, D[2], 0, 0, 0);
        D[3] = __builtin_amdgcn_mfma_f32_16x16x32_f16(v1, bw2_33, D[3], 0, 0, 0);
        initb(Cacc, bias1);                       // reborn as gates1(t+1)
        Cacc[0] = __builtin_amdgcn_mfma_f32_16x16x32_f16(u0, bw1_00, Cacc[0], 0, 0, 0);
        Cacc[1] = __builtin_amdgcn_mfma_f32_16x16x32_f16(u0, bw1_01, Cacc[1], 0, 0, 0);
        Cacc[2] = __builtin_amdgcn_mfma_f32_16x16x32_f16(u0, bw1_02, Cacc[2], 0, 0, 0);
        Cacc[3] = __builtin_amdgcn_mfma_f32_16x16x32_f16(u0, bw1_03, Cacc[3], 0, 0, 0);
        Cacc[0] = __builtin_amdgcn_mfma_f32_16x16x32_f16(u1, bw1_10, Cacc[0], 0, 0, 0);
        Cacc[1] = __builtin_amdgcn_mfma_f32_16x16x32_f16(u1, bw1_11, Cacc[1], 0, 0, 0);
        Cacc[2] = __builtin_amdgcn_mfma_f32_16x16x32_f16(u1, bw1_12, Cacc[2], 0, 0, 0);
        Cacc[3] = __builtin_amdgcn_mfma_f32_16x16x32_f16(u1, bw1_13, Cacc[3], 0, 0, 0);
        Cacc[0] = __builtin_amdgcn_mfma_f32_16x16x32_f16(axn, bw1_20, Cacc[0], 0, 0, 0);
        Cacc[1] = __builtin_amdgcn_mfma_f32_16x16x32_f16(axn, bw1_21, Cacc[1], 0, 0, 0);
        Cacc[2] = __builtin_amdgcn_mfma_f32_16x16x32_f16(axn, bw1_22, Cacc[2], 0, 0, 0);
        Cacc[3] = __builtin_amdgcn_mfma_f32_16x16x32_f16(axn, bw1_23, Cacc[3], 0, 0, 0);
        cell_update(D, cs2, h2w);
    };

    #define PIN_ALL() do {                                                      \
        asm volatile("" :                                                       \
            "+v"(bw1_00), "+v"(bw1_01), "+v"(bw1_02), "+v"(bw1_03),             \
            "+v"(bw1_10), "+v"(bw1_11), "+v"(bw1_12), "+v"(bw1_13),             \
            "+v"(bw1_20), "+v"(bw1_21), "+v"(bw1_22), "+v"(bw1_23));            \
        asm volatile("" :                                                       \
            "+v"(bw2_00), "+v"(bw2_01), "+v"(bw2_02), "+v"(bw2_03),             \
            "+v"(bw2_10), "+v"(bw2_11), "+v"(bw2_12), "+v"(bw2_13),             \
            "+v"(bw2_20), "+v"(bw2_21), "+v"(bw2_22), "+v"(bw2_23),             \
            "+v"(bw2_30), "+v"(bw2_31), "+v"(bw2_32), "+v"(bw2_33),             \
            "+v"(bias1[0]), "+v"(bias1[1]), "+v"(bias1[2]), "+v"(bias1[3]),     \
            "+v"(bias2[0]), "+v"(bias2[1]), "+v"(bias2[2]), "+v"(bias2[3]));    \
    } while (0)

    // ---- preloop: CP/CQ = gates1(0) = b1 + Wx*x(0); prefetch x(1)
    prefetch_tile(xbP, cxP, cx8P, 0);
    prefetch_tile(xbQ, cxQ, cx8Q, 0);
    f32x4 CP[4], CQ[4];
    {
        half8 ax0 = build_ax2(cxP, cx8P);
        initb(CP, bias1);
        CP[0] = __builtin_amdgcn_mfma_f32_16x16x32_f16(ax0, bw1_20, CP[0], 0, 0, 0);
        CP[1] = __builtin_amdgcn_mfma_f32_16x16x32_f16(ax0, bw1_21, CP[1], 0, 0, 0);
        CP[2] = __builtin_amdgcn_mfma_f32_16x16x32_f16(ax0, bw1_22, CP[2], 0, 0, 0);
        CP[3] = __builtin_amdgcn_mfma_f32_16x16x32_f16(ax0, bw1_23, CP[3], 0, 0, 0);
        half8 ax1 = build_ax2(cxQ, cx8Q);
        initb(CQ, bias1);
        CQ[0] = __builtin_amdgcn_mfma_f32_16x16x32_f16(ax1, bw1_20, CQ[0], 0, 0, 0);
        CQ[1] = __builtin_amdgcn_mfma_f32_16x16x32_f16(ax1, bw1_21, CQ[1], 0, 0, 0);
        CQ[2] = __builtin_amdgcn_mfma_f32_16x16x32_f16(ax1, bw1_22, CQ[2], 0, 0, 0);
        CQ[3] = __builtin_amdgcn_mfma_f32_16x16x32_f16(ax1, bw1_23, CQ[3], 0, 0, 0);
    }
    prefetch_tile(xbP, cxP, cx8P, 1);
    prefetch_tile(xbQ, cxQ, cx8Q, 1);
    __syncthreads();                      // zero h state visible

    for (int t = 0; t < T_STEPS; t += 2) {
        // ============ step t (even): writes parity 1, reads h2 parity 0
        PIN_ALL();
        half8 axP = build_ax2(cxP, cx8P);          // x(t+1)
        half8 axQ = build_ax2(cxQ, cx8Q);
        prefetch_tile(xbP, cxP, cx8P, t + 2 < T_STEPS ? t + 2 : T_STEPS - 1);
        prefetch_tile(xbQ, cxQ, cx8Q, t + 2 < T_STEPS ? t + 2 : T_STEPS - 1);
        cell_update(CP, c1P, &h1P[1][0][0]);
        cell_update(CQ, c1Q, &h1Q[1][0][0]);
        __syncthreads();                           // h1(t) both tiles visible
        tile_phase(CP, c2P, &h1P[1][0][0], &h2P[0][0][0], &h2P[1][0][0], axP);
        tile_phase(CQ, c2Q, &h1Q[1][0][0], &h2Q[0][0][0], &h2Q[1][0][0], axQ);

        // ============ step t+1 (odd): writes parity 0, reads h2 parity 1
        PIN_ALL();
        half8 bxP = build_ax2(cxP, cx8P);          // x(t+2)
        half8 bxQ = build_ax2(cxQ, cx8Q);
        prefetch_tile(xbP, cxP, cx8P, t + 3 < T_STEPS ? t + 3 : T_STEPS - 1);
        prefetch_tile(xbQ, cxQ, cx8Q, t + 3 < T_STEPS ? t + 3 : T_STEPS - 1);
        cell_update(CP, c1P, &h1P[0][0][0]);
        cell_update(CQ, c1Q, &h1Q[0][0][0]);
        __syncthreads();                           // h1(t+1) visible
        tile_phase(CP, c2P, &h1P[0][0][0], &h2P[1][0][0], &h2P[0][0][0], bxP);
        tile_phase(CQ, c2Q, &h1Q[0][0][0], &h2Q[1][0][0], &h2Q[0][0][0], bxQ);
    }
    __syncthreads();   // final h2 writes visible

    // ---- output head: 32 batches x 3 outs = 96 threads; h2(199) in parity 0
    if (tid < 96) {
        int bl = tid / 3, o = tid - bl * 3;
        const _Float16* src = (bl < 16) ? &h2P[0][bl][0] : &h2Q[0][bl - 16][0];
        float acc = bout[o];
        #pragma unroll 8
        for (int pos = 0; pos < HDIM; ++pos) {
            int sub = pos & 31;
            int j = (pos >> 5) * 32 + (((sub >> 2) & 1) << 4) + ((sub >> 3) << 2) + (sub & 3);
            acc = __builtin_fmaf(Wout[o * 64 + j], (float)src[pos], acc);
        }
        out[(bbase + bl) * 3 + o] = acc;
    }
    #undef PIN_ALL
}

extern "C" void kernel_launch(void* const* d_in, const int* in_sizes, int n_in,
                              void* d_out, int out_size, void* d_ws, size_t ws_size,
                              hipStream_t stream) {
    const float* x     = (const float*)d_in[0];
    const float* Wih1  = (const float*)d_in[1];
    const float* Whh1  = (const float*)d_in[2];
    const float* bih1  = (const float*)d_in[3];
    const float* bhh1  = (const float*)d_in[4];
    const float* Wih2  = (const float*)d_in[5];
    const float* Whh2  = (const float*)d_in[6];
    const float* bih2  = (const float*)d_in[7];
    const float* bhh2  = (const float*)d_in[8];
    const float* Wout  = (const float*)d_in[9];
    const float* bout  = (const float*)d_in[10];
    float* ws  = (float*)d_ws;
    float* out = (float*)d_out;

    pack_kernel<<<(PACK_TOT + 255) / 256, 256, 0, stream>>>(
        Wih1, Whh1, bih1, bhh1, Wih2, Whh2, bih2, bhh2, ws);

    lstm_mfma<<<B_TOT / 32, 256, 0, stream>>>(x, ws, Wout, bout, out);
}

// Round 11
// 500.696 us; speedup vs baseline: 1.3021x; 1.3021x over previous
//
#include <hip/hip_runtime.h>
#include <hip/hip_bf16.h>

// LSTM: B=16384, T=200, IN=9, H=64, OUT=3, 2 layers + linear head.
// Round 11: R8 host + packed-f32 (v_pk_*_f32) cell glue, pair-wise rcp batch.
//   R9/R10 dual-tile abandoned (spill / VGPR-AGPR shuffling + serialization).
// Block = 16 batches, 256 threads (4 waves). Grid = 1024 blocks.
// Wave w owns gate n-tiles {w, w+4, w+8, w+12}.
// Fragment layouts (gfx950 16x16x32, verified R2-R10):
//   A: lane l holds A[m=l&15][k=4*(l>>4)+(j&3)+16*(j>>2)]
//   B: lane l holds B[k=...][n=l&15]
//   C/D: col=l&15, row=(l>>4)*4+reg
// LDS h-state k-PERMUTED (R3). Weight pre-scale (R7): i,f,o x(-log2e), g x(-2log2e).
// cell math: merged-reciprocal, glue in f32x2 (packed), 2-way rcp per pair.

#define B_TOT   16384
#define T_STEPS 200
#define IN_DIM  9
#define HDIM    64

#define PK1_OFF 0         // [3][16][64][8] = 24576 f16
#define PK2_OFF 24576     // [4][16][64][8] = 32768 f16
#define BSUM_HALF_OFF 57344   // then 512 f32 (b1[256], b2[256])
#define PACK_W_TOT 57344
#define PACK_TOT (PACK_W_TOT + 512)

#define L2E     1.44269504089f
#define TWOL2E  2.88539008178f

typedef _Float16 half8  __attribute__((ext_vector_type(8)));
typedef _Float16 half4v __attribute__((ext_vector_type(4)));
typedef float    f32x4  __attribute__((ext_vector_type(4)));
typedef float    f32x2  __attribute__((ext_vector_type(2)));
typedef float    f4u    __attribute__((ext_vector_type(4), aligned(4)));

// ---------------- prep: repack weights (B-frag layout, scales folded) -------
__global__ void pack_kernel(const float* __restrict__ Wih1, const float* __restrict__ Whh1,
                            const float* __restrict__ bih1, const float* __restrict__ bhh1,
                            const float* __restrict__ Wih2, const float* __restrict__ Whh2,
                            const float* __restrict__ bih2, const float* __restrict__ bhh2,
                            float* __restrict__ ws) {
    int e = blockIdx.x * 256 + threadIdx.x;
    if (e >= PACK_TOT) return;
    _Float16* wh = (_Float16*)ws;
    float* bptr = (float*)(wh + BSUM_HALF_OFF);
    auto gscale = [](int q) -> float {
        int gt = q >> 6;                       // 0=i,1=f,2=g,3=o
        return (gt == 2) ? (-2.0f * L2E) : -L2E;
    };
    if (e < PK2_OFF) {
        int j = e & 7, lane = (e >> 3) & 63, nt = (e >> 9) & 15, c = e >> 13;
        int k = c * 32 + 4 * (lane >> 4) + (j & 3) + 16 * (j >> 2);
        int q = nt * 16 + (lane & 15);
        float v = 0.0f;
        if (k < 64)      v = Whh1[q * 64 + k];
        else if (k < 73) v = Wih1[q * 9 + (k - 64)];
        wh[e] = (_Float16)(v * gscale(q));
    } else if (e < PACK_W_TOT) {
        int e2 = e - PK2_OFF;
        int j = e2 & 7, lane = (e2 >> 3) & 63, nt = (e2 >> 9) & 15, c = e2 >> 13;
        int k = c * 32 + 4 * (lane >> 4) + (j & 3) + 16 * (j >> 2);
        int q = nt * 16 + (lane & 15);
        float v = (k < 64) ? Wih2[q * 64 + k] : Whh2[q * 64 + (k - 64)];
        wh[e] = (_Float16)(v * gscale(q));
    } else if (e < PACK_W_TOT + 256) {
        int q = e - PACK_W_TOT;
        bptr[q] = (bih1[q] + bhh1[q]) * gscale(q);
    } else {
        int q = e - PACK_W_TOT - 256;
        bptr[256 + q] = (bih2[q] + bhh2[q]) * gscale(q);
    }
}

// ---------------- main sequential LSTM ----------------
__global__ __launch_bounds__(256, 2) void lstm_mfma(
    const float* __restrict__ x,
    const float* __restrict__ ws_f,
    const float* __restrict__ Wout,
    const float* __restrict__ bout,
    float* __restrict__ out)
{
    const int tid  = threadIdx.x;
    const int lane = tid & 63;
    const int w    = __builtin_amdgcn_readfirstlane(tid >> 6);   // 0..3
    const int l15  = lane & 15;
    const int l4   = lane >> 4;

    const _Float16* wh  = (const _Float16*)ws_f;
    const _Float16* pk1 = wh + PK1_OFF;
    const _Float16* pk2 = wh + PK2_OFF;
    const float* bsum   = (const float*)(wh + BSUM_HALF_OFF);

    __shared__ _Float16 h1s[2][16][72];
    __shared__ _Float16 h2s[2][16][72];
    __shared__ _Float16 xwin[2][8][4][16][4];   // [buf][step&7][quad][batch][4]

    for (int i = tid; i < 2 * 16 * 72; i += 256) {
        (&h1s[0][0][0])[i] = (_Float16)0.0f;
        (&h2s[0][0][0])[i] = (_Float16)0.0f;
    }
    for (int i = tid; i < 2 * 8 * 4 * 16 * 4; i += 256)
        (&xwin[0][0][0][0][0])[i] = (_Float16)0.0f;

    const int bbase = blockIdx.x * 16;

    // ---- x loader (R8): thread handles batch b_=tid&15, entries z_ and z_+16
    const int b_ = tid & 15, z_ = tid >> 4;
    const int s0_ = (z_ * 11) >> 5, q0_ = z_ - 3 * s0_;
    const bool act1 = (z_ < 8);
    const int pz1 = z_ + 16;
    const int s1_ = (pz1 * 11) >> 5, q1_ = pz1 - 3 * s1_;
    const float* xbL = x + (long)(bbase + b_) * (T_STEPS * IN_DIM);

    f4u pfA = {0.f, 0.f, 0.f, 0.f}, pfB = {0.f, 0.f, 0.f, 0.f};
    auto fetch_x = [&](int wb) {
        int t0 = wb + s0_; if (t0 > T_STEPS - 1) t0 = T_STEPS - 1;
        const float* p0 = xbL + t0 * IN_DIM + 4 * q0_;
        if (q0_ < 2) pfA = *(const f4u*)p0; else pfA[0] = p0[0];
        if (act1) {
            int t1 = wb + s1_; if (t1 > T_STEPS - 1) t1 = T_STEPS - 1;
            const float* p1 = xbL + t1 * IN_DIM + 4 * q1_;
            if (q1_ < 2) pfB = *(const f4u*)p1; else pfB[0] = p1[0];
        }
    };
    auto store_x = [&](int buf) {
        f4u A = pfA, B = pfB;
        if (q0_ == 2) { A[1] = 0.f; A[2] = 0.f; A[3] = 0.f; }
        half4v hv;
        hv[0] = (_Float16)A[0]; hv[1] = (_Float16)A[1];
        hv[2] = (_Float16)A[2]; hv[3] = (_Float16)A[3];
        *(half4v*)&xwin[buf][s0_][q0_][b_][0] = hv;
        if (act1) {
            if (q1_ == 2) { B[1] = 0.f; B[2] = 0.f; B[3] = 0.f; }
            half4v hw;
            hw[0] = (_Float16)B[0]; hw[1] = (_Float16)B[1];
            hw[2] = (_Float16)B[2]; hw[3] = (_Float16)B[3];
            *(half4v*)&xwin[buf][s1_][q1_][b_][0] = hw;
        }
    };
    auto read_ax = [&](int tt) -> half8 {
        half4v xq = *(const half4v*)&xwin[(tt >> 3) & 1][tt & 7][l4][l15][0];
        return __builtin_shufflevector(xq, xq, 0, 1, 2, 3, 0, 1, 2, 3);
    };

    // ---- weight B-fragments: 28 x half8, loop-pinned
    half8 bw1_00, bw1_01, bw1_02, bw1_03;
    half8 bw1_10, bw1_11, bw1_12, bw1_13;
    half8 bw1_20, bw1_21, bw1_22, bw1_23;
    half8 bw2_00, bw2_01, bw2_02, bw2_03;
    half8 bw2_10, bw2_11, bw2_12, bw2_13;
    half8 bw2_20, bw2_21, bw2_22, bw2_23;
    half8 bw2_30, bw2_31, bw2_32, bw2_33;
    {
        #define LD1(c,g) *(const half8*)(pk1 + (((c * 16) + (w + 4 * g)) * 64 + lane) * 8)
        #define LD2(c,g) *(const half8*)(pk2 + (((c * 16) + (w + 4 * g)) * 64 + lane) * 8)
        bw1_00 = LD1(0,0); bw1_01 = LD1(0,1); bw1_02 = LD1(0,2); bw1_03 = LD1(0,3);
        bw1_10 = LD1(1,0); bw1_11 = LD1(1,1); bw1_12 = LD1(1,2); bw1_13 = LD1(1,3);
        bw1_20 = LD1(2,0); bw1_21 = LD1(2,1); bw1_22 = LD1(2,2); bw1_23 = LD1(2,3);
        bw2_00 = LD2(0,0); bw2_01 = LD2(0,1); bw2_02 = LD2(0,2); bw2_03 = LD2(0,3);
        bw2_10 = LD2(1,0); bw2_11 = LD2(1,1); bw2_12 = LD2(1,2); bw2_13 = LD2(1,3);
        bw2_20 = LD2(2,0); bw2_21 = LD2(2,1); bw2_22 = LD2(2,2); bw2_23 = LD2(2,3);
        bw2_30 = LD2(3,0); bw2_31 = LD2(3,1); bw2_32 = LD2(3,2); bw2_33 = LD2(3,3);
        #undef LD1
        #undef LD2
    }

    float bias1[4], bias2[4];
    #pragma unroll
    for (int g = 0; g < 4; ++g) {
        bias1[g] = bsum[(w + 4 * g) * 16 + l15];
        bias2[g] = bsum[256 + (w + 4 * g) * 16 + l15];
    }

    const int hpos = ((w >> 1) << 5) + 8 * (l15 >> 2) + (l15 & 3) + ((w & 1) << 2);

    f32x4 c1 = {0.f, 0.f, 0.f, 0.f};
    f32x4 c2 = {0.f, 0.f, 0.f, 0.f};

    // ---- packed-f32 cell pair: 2 cells (rows rb, rb+1) via f32x2 glue.
    // Scalar: exp2 (trans), bit tricks. Packed: all add/mul/fma.
    auto cell_pair = [&](f32x2 Gi, f32x2 Gf, f32x2 Gg, f32x2 Go,
                         f32x2& cs, _Float16* hb, int rb) {
        const f32x2 one = {1.0f, 1.0f};
        f32x2 ei, ef, eg, eo;
        ei.x = __builtin_amdgcn_exp2f(Gi.x); ei.y = __builtin_amdgcn_exp2f(Gi.y);
        ef.x = __builtin_amdgcn_exp2f(Gf.x); ef.y = __builtin_amdgcn_exp2f(Gf.y);
        eg.x = __builtin_amdgcn_exp2f(Gg.x); eg.y = __builtin_amdgcn_exp2f(Gg.y);
        eo.x = __builtin_amdgcn_exp2f(Go.x); eo.y = __builtin_amdgcn_exp2f(Go.y);
        f32x2 ai = ei + one, af = ef + one, ag = eg + one;
        f32x2 gm = one - eg;
        f32x2 pp = ai * ag;
        f32x2 num = gm * af + cs * pp;        // pk_mul + pk_fma
        f32x2 den = af * pp;
        float s  = den.x * den.y;
        float rs = __builtin_amdgcn_rcpf(s);
        f32x2 inv = {rs * den.y, rs * den.x};
        f32x2 cc = num * inv;
        cs = cc;
        f32x2 z = cc * (f32x2){TWOL2E, TWOL2E};
        int zx = __float_as_int(z.x), zy = __float_as_int(z.y);
        f32x2 ec;
        ec.x = __builtin_amdgcn_exp2f(__int_as_float(zx | (int)0x80000000));
        ec.y = __builtin_amdgcn_exp2f(__int_as_float(zy | (int)0x80000000));
        f32x2 tm = one - ec;
        f32x2 d2 = (eo + one) * (ec + one);
        float t  = d2.x * d2.y;
        float rt = __builtin_amdgcn_rcpf(t);
        f32x2 jnv = {rt * d2.y, rt * d2.x};
        f32x2 hsv;
        hsv.x = __int_as_float(__float_as_int(tm.x) ^ (zx & (int)0x80000000));
        hsv.y = __int_as_float(__float_as_int(tm.y) ^ (zy & (int)0x80000000));
        f32x2 hv = hsv * jnv;
        hb[(4 * l4 + rb)     * 72 + hpos] = (_Float16)hv.x;
        hb[(4 * l4 + rb + 1) * 72 + hpos] = (_Float16)hv.y;
    };

    auto cell_update = [&](f32x4* G, f32x4& cs, _Float16* hb) {
        f32x2 csL = {cs[0], cs[1]}, csH = {cs[2], cs[3]};
        cell_pair((f32x2){G[0][0], G[0][1]}, (f32x2){G[1][0], G[1][1]},
                  (f32x2){G[2][0], G[2][1]}, (f32x2){G[3][0], G[3][1]},
                  csL, hb, 0);
        cell_pair((f32x2){G[0][2], G[0][3]}, (f32x2){G[1][2], G[1][3]},
                  (f32x2){G[2][2], G[2][3]}, (f32x2){G[3][2], G[3][3]},
                  csH, hb, 2);
        cs[0] = csL.x; cs[1] = csL.y; cs[2] = csH.x; cs[3] = csH.y;
    };

    #define PIN_ALL() do {                                                      \
        asm volatile("" :                                                       \
            "+v"(bw1_00), "+v"(bw1_01), "+v"(bw1_02), "+v"(bw1_03),             \
            "+v"(bw1_10), "+v"(bw1_11), "+v"(bw1_12), "+v"(bw1_13),             \
            "+v"(bw1_20), "+v"(bw1_21), "+v"(bw1_22), "+v"(bw1_23));            \
        asm volatile("" :                                                       \
            "+v"(bw2_00), "+v"(bw2_01), "+v"(bw2_02), "+v"(bw2_03),             \
            "+v"(bw2_10), "+v"(bw2_11), "+v"(bw2_12), "+v"(bw2_13),             \
            "+v"(bw2_20), "+v"(bw2_21), "+v"(bw2_22), "+v"(bw2_23),             \
            "+v"(bw2_30), "+v"(bw2_31), "+v"(bw2_32), "+v"(bw2_33),             \
            "+v"(bias1[0]), "+v"(bias1[1]), "+v"(bias1[2]), "+v"(bias1[3]),     \
            "+v"(bias2[0]), "+v"(bias2[1]), "+v"(bias2[2]), "+v"(bias2[3]));    \
    } while (0)

    // ---- preloop: fill x window 0, prefetch window 1, init C = gates1(0)
    fetch_x(0);
    __syncthreads();              // LDS zeros committed before store_x
    store_x(0);                   // buf0 = x(0..7)
    fetch_x(8);                   // regs = x(8..15), stored at t=0
    __syncthreads();              // window 0 + zero h state visible

    f32x4 C[4];
    {
        half8 ax0 = read_ax(0);
        #pragma unroll
        for (int g = 0; g < 4; ++g) C[g] = (f32x4){bias1[g], bias1[g], bias1[g], bias1[g]};
        C[0] = __builtin_amdgcn_mfma_f32_16x16x32_f16(ax0, bw1_20, C[0], 0, 0, 0);
        C[1] = __builtin_amdgcn_mfma_f32_16x16x32_f16(ax0, bw1_21, C[1], 0, 0, 0);
        C[2] = __builtin_amdgcn_mfma_f32_16x16x32_f16(ax0, bw1_22, C[2], 0, 0, 0);
        C[3] = __builtin_amdgcn_mfma_f32_16x16x32_f16(ax0, bw1_23, C[3], 0, 0, 0);
    }

    for (int t = 0; t < T_STEPS; t += 2) {
        // ================= body A (even t): writes h buf[1], reads h2 buf[0]
        PIN_ALL();
        cell_update(C, c1, &h1s[1][0][0]);
        if ((t & 7) == 0) {
            store_x(((t >> 3) + 1) & 1);
            fetch_x(t + 16);
        }
        __syncthreads();                      // h1(t) visible

        half8 a10  = *(const half8*)&h1s[1][l15][ 0 + 8 * l4];
        half8 a11  = *(const half8*)&h1s[1][l15][32 + 8 * l4];
        half8 a2h0 = *(const half8*)&h2s[0][l15][ 0 + 8 * l4];
        half8 a2h1 = *(const half8*)&h2s[0][l15][32 + 8 * l4];
        half8 ax   = read_ax(t + 1);

        f32x4 D[4];
        #pragma unroll
        for (int g = 0; g < 4; ++g) D[g] = (f32x4){bias2[g], bias2[g], bias2[g], bias2[g]};
        D[0] = __builtin_amdgcn_mfma_f32_16x16x32_f16(a10,  bw2_00, D[0], 0, 0, 0);
        D[1] = __builtin_amdgcn_mfma_f32_16x16x32_f16(a10,  bw2_01, D[1], 0, 0, 0);
        D[2] = __builtin_amdgcn_mfma_f32_16x16x32_f16(a10,  bw2_02, D[2], 0, 0, 0);
        D[3] = __builtin_amdgcn_mfma_f32_16x16x32_f16(a10,  bw2_03, D[3], 0, 0, 0);
        D[0] = __builtin_amdgcn_mfma_f32_16x16x32_f16(a11,  bw2_10, D[0], 0, 0, 0);
        D[1] = __builtin_amdgcn_mfma_f32_16x16x32_f16(a11,  bw2_11, D[1], 0, 0, 0);
        D[2] = __builtin_amdgcn_mfma_f32_16x16x32_f16(a11,  bw2_12, D[2], 0, 0, 0);
        D[3] = __builtin_amdgcn_mfma_f32_16x16x32_f16(a11,  bw2_13, D[3], 0, 0, 0);
        D[0] = __builtin_amdgcn_mfma_f32_16x16x32_f16(a2h0, bw2_20, D[0], 0, 0, 0);
        D[1] = __builtin_amdgcn_mfma_f32_16x16x32_f16(a2h0, bw2_21, D[1], 0, 0, 0);
        D[2] = __builtin_amdgcn_mfma_f32_16x16x32_f16(a2h0, bw2_22, D[2], 0, 0, 0);
        D[3] = __builtin_amdgcn_mfma_f32_16x16x32_f16(a2h0, bw2_23, D[3], 0, 0, 0);
        D[0] = __builtin_amdgcn_mfma_f32_16x16x32_f16(a2h1, bw2_30, D[0], 0, 0, 0);
        D[1] = __builtin_amdgcn_mfma_f32_16x16x32_f16(a2h1, bw2_31, D[1], 0, 0, 0);
        D[2] = __builtin_amdgcn_mfma_f32_16x16x32_f16(a2h1, bw2_32, D[2], 0, 0, 0);
        D[3] = __builtin_amdgcn_mfma_f32_16x16x32_f16(a2h1, bw2_33, D[3], 0, 0, 0);

        f32x4 CB[4];
        #pragma unroll
        for (int g = 0; g < 4; ++g) CB[g] = (f32x4){bias1[g], bias1[g], bias1[g], bias1[g]};
        CB[0] = __builtin_amdgcn_mfma_f32_16x16x32_f16(a10, bw1_00, CB[0], 0, 0, 0);
        CB[1] = __builtin_amdgcn_mfma_f32_16x16x32_f16(a10, bw1_01, CB[1], 0, 0, 0);
        CB[2] = __builtin_amdgcn_mfma_f32_16x16x32_f16(a10, bw1_02, CB[2], 0, 0, 0);
        CB[3] = __builtin_amdgcn_mfma_f32_16x16x32_f16(a10, bw1_03, CB[3], 0, 0, 0);
        CB[0] = __builtin_amdgcn_mfma_f32_16x16x32_f16(a11, bw1_10, CB[0], 0, 0, 0);
        CB[1] = __builtin_amdgcn_mfma_f32_16x16x32_f16(a11, bw1_11, CB[1], 0, 0, 0);
        CB[2] = __builtin_amdgcn_mfma_f32_16x16x32_f16(a11, bw1_12, CB[2], 0, 0, 0);
        CB[3] = __builtin_amdgcn_mfma_f32_16x16x32_f16(a11, bw1_13, CB[3], 0, 0, 0);
        CB[0] = __builtin_amdgcn_mfma_f32_16x16x32_f16(ax,  bw1_20, CB[0], 0, 0, 0);
        CB[1] = __builtin_amdgcn_mfma_f32_16x16x32_f16(ax,  bw1_21, CB[1], 0, 0, 0);
        CB[2] = __builtin_amdgcn_mfma_f32_16x16x32_f16(ax,  bw1_22, CB[2], 0, 0, 0);
        CB[3] = __builtin_amdgcn_mfma_f32_16x16x32_f16(ax,  bw1_23, CB[3], 0, 0, 0);

        cell_update(D, c2, &h2s[1][0][0]);

        // ================= body B (odd t+1): writes h buf[0], reads h2 buf[1]
        PIN_ALL();
        cell_update(CB, c1, &h1s[0][0][0]);
        __syncthreads();                      // h1(t+1) visible

        half8 b10  = *(const half8*)&h1s[0][l15][ 0 + 8 * l4];
        half8 b11  = *(const half8*)&h1s[0][l15][32 + 8 * l4];
        half8 b2h0 = *(const half8*)&h2s[1][l15][ 0 + 8 * l4];
        half8 b2h1 = *(const half8*)&h2s[1][l15][32 + 8 * l4];
        half8 bx   = read_ax(t + 2);

        f32x4 E[4];
        #pragma unroll
        for (int g = 0; g < 4; ++g) E[g] = (f32x4){bias2[g], bias2[g], bias2[g], bias2[g]};
        E[0] = __builtin_amdgcn_mfma_f32_16x16x32_f16(b10,  bw2_00, E[0], 0, 0, 0);
        E[1] = __builtin_amdgcn_mfma_f32_16x16x32_f16(b10,  bw2_01, E[1], 0, 0, 0);
        E[2] = __builtin_amdgcn_mfma_f32_16x16x32_f16(b10,  bw2_02, E[2], 0, 0, 0);
        E[3] = __builtin_amdgcn_mfma_f32_16x16x32_f16(b10,  bw2_03, E[3], 0, 0, 0);
        E[0] = __builtin_amdgcn_mfma_f32_16x16x32_f16(b11,  bw2_10, E[0], 0, 0, 0);
        E[1] = __builtin_amdgcn_mfma_f32_16x16x32_f16(b11,  bw2_11, E[1], 0, 0, 0);
        E[2] = __builtin_amdgcn_mfma_f32_16x16x32_f16(b11,  bw2_12, E[2], 0, 0, 0);
        E[3] = __builtin_amdgcn_mfma_f32_16x16x32_f16(b11,  bw2_13, E[3], 0, 0, 0);
        E[0] = __builtin_amdgcn_mfma_f32_16x16x32_f16(b2h0, bw2_20, E[0], 0, 0, 0);
        E[1] = __builtin_amdgcn_mfma_f32_16x16x32_f16(b2h0, bw2_21, E[1], 0, 0, 0);
        E[2] = __builtin_amdgcn_mfma_f32_16x16x32_f16(b2h0, bw2_22, E[2], 0, 0, 0);
        E[3] = __builtin_amdgcn_mfma_f32_16x16x32_f16(b2h0, bw2_23, E[3], 0, 0, 0);
        E[0] = __builtin_amdgcn_mfma_f32_16x16x32_f16(b2h1, bw2_30, E[0], 0, 0, 0);
        E[1] = __builtin_amdgcn_mfma_f32_16x16x32_f16(b2h1, bw2_31, E[1], 0, 0, 0);
        E[2] = __builtin_amdgcn_mfma_f32_16x16x32_f16(b2h1, bw2_32, E[2], 0, 0, 0);
        E[3] = __builtin_amdgcn_mfma_f32_16x16x32_f16(b2h1, bw2_33, E[3], 0, 0, 0);

        #pragma unroll
        for (int g = 0; g < 4; ++g) C[g] = (f32x4){bias1[g], bias1[g], bias1[g], bias1[g]};
        C[0] = __builtin_amdgcn_mfma_f32_16x16x32_f16(b10, bw1_00, C[0], 0, 0, 0);
        C[1] = __builtin_amdgcn_mfma_f32_16x16x32_f16(b10, bw1_01, C[1], 0, 0, 0);
        C[2] = __builtin_amdgcn_mfma_f32_16x16x32_f16(b10, bw1_02, C[2], 0, 0, 0);
        C[3] = __builtin_amdgcn_mfma_f32_16x16x32_f16(b10, bw1_03, C[3], 0, 0, 0);
        C[0] = __builtin_amdgcn_mfma_f32_16x16x32_f16(b11, bw1_10, C[0], 0, 0, 0);
        C[1] = __builtin_amdgcn_mfma_f32_16x16x32_f16(b11, bw1_11, C[1], 0, 0, 0);
        C[2] = __builtin_amdgcn_mfma_f32_16x16x32_f16(b11, bw1_12, C[2], 0, 0, 0);
        C[3] = __builtin_amdgcn_mfma_f32_16x16x32_f16(b11, bw1_13, C[3], 0, 0, 0);
        C[0] = __builtin_amdgcn_mfma_f32_16x16x32_f16(bx,  bw1_20, C[0], 0, 0, 0);
        C[1] = __builtin_amdgcn_mfma_f32_16x16x32_f16(bx,  bw1_21, C[1], 0, 0, 0);
        C[2] = __builtin_amdgcn_mfma_f32_16x16x32_f16(bx,  bw1_22, C[2], 0, 0, 0);
        C[3] = __builtin_amdgcn_mfma_f32_16x16x32_f16(bx,  bw1_23, C[3], 0, 0, 0);

        cell_update(E, c2, &h2s[0][0][0]);
    }
    __syncthreads();   // final h2 writes visible

    // ---- output head: h2(199) in h2s[0] (perm-stored)
    if (tid < 48) {
        int bl = tid / 3, o = tid - bl * 3;
        float acc = bout[o];
        #pragma unroll 8
        for (int pos = 0; pos < HDIM; ++pos) {
            int sub = pos & 31;
            int j = (pos >> 5) * 32 + (((sub >> 2) & 1) << 4) + ((sub >> 3) << 2) + (sub & 3);
            acc = __builtin_fmaf(Wout[o * 64 + j], (float)h2s[0][bl][pos], acc);
        }
        out[(bbase + bl) * 3 + o] = acc;
    }
    #undef PIN_ALL
}

extern "C" void kernel_launch(void* const* d_in, const int* in_sizes, int n_in,
                              void* d_out, int out_size, void* d_ws, size_t ws_size,
                              hipStream_t stream) {
    const float* x     = (const float*)d_in[0];
    const float* Wih1  = (const float*)d_in[1];
    const float* Whh1  = (const float*)d_in[2];
    const float* bih1  = (const float*)d_in[3];
    const float* bhh1  = (const float*)d_in[4];
    const float* Wih2  = (const float*)d_in[5];
    const float* Whh2  = (const float*)d_in[6];
    const float* bih2  = (const float*)d_in[7];
    const float* bhh2  = (const float*)d_in[8];
    const float* Wout  = (const float*)d_in[9];
    const float* bout  = (const float*)d_in[10];
    float* ws  = (float*)d_ws;
    float* out = (float*)d_out;

    pack_kernel<<<(PACK_TOT + 255) / 256, 256, 0, stream>>>(
        Wih1, Whh1, bih1, bhh1, Wih2, Whh2, bih2, bhh2, ws);

    lstm_mfma<<<B_TOT / 16, 256, 0, stream>>>(x, ws, Wout, bout, out);
}

// Round 12
// 499.991 us; speedup vs baseline: 1.3039x; 1.0014x over previous
//
#include <hip/hip_runtime.h>
#include <hip/hip_bf16.h>

// LSTM: B=16384, T=200, IN=9, H=64, OUT=3, 2 layers + linear head.
// Round 12: R11 host + scheduling-freedom micro-opts:
//   (1) ONE register-pin per unrolled iteration (each asm = sched fence),
//   (2) adjacent cell_updates (L2(t) + L1(t+1)) -> 8 interleavable exp chains,
//   (3) read_ax hoisted pre-barrier (xwin visible since >=8-step-old barrier).
// Block = 16 batches, 256 threads (4 waves). Grid = 1024 blocks.
// Wave w owns gate n-tiles {w, w+4, w+8, w+12}.
// Fragment layouts (gfx950 16x16x32, verified R2-R11):
//   A: lane l holds A[m=l&15][k=4*(l>>4)+(j&3)+16*(j>>2)]
//   B: lane l holds B[k=...][n=l&15]
//   C/D: col=l&15, row=(l>>4)*4+reg
// LDS h-state k-PERMUTED (R3). Weight pre-scale (R7): i,f,o x(-log2e), g x(-2log2e).
// cell math (R11): merged-reciprocal, packed f32x2 glue, 2-way rcp per pair.

#define B_TOT   16384
#define T_STEPS 200
#define IN_DIM  9
#define HDIM    64

#define PK1_OFF 0         // [3][16][64][8] = 24576 f16
#define PK2_OFF 24576     // [4][16][64][8] = 32768 f16
#define BSUM_HALF_OFF 57344   // then 512 f32 (b1[256], b2[256])
#define PACK_W_TOT 57344
#define PACK_TOT (PACK_W_TOT + 512)

#define L2E     1.44269504089f
#define TWOL2E  2.88539008178f

typedef _Float16 half8  __attribute__((ext_vector_type(8)));
typedef _Float16 half4v __attribute__((ext_vector_type(4)));
typedef float    f32x4  __attribute__((ext_vector_type(4)));
typedef float    f32x2  __attribute__((ext_vector_type(2)));
typedef float    f4u    __attribute__((ext_vector_type(4), aligned(4)));

// ---------------- prep: repack weights (B-frag layout, scales folded) -------
__global__ void pack_kernel(const float* __restrict__ Wih1, const float* __restrict__ Whh1,
                            const float* __restrict__ bih1, const float* __restrict__ bhh1,
                            const float* __restrict__ Wih2, const float* __restrict__ Whh2,
                            const float* __restrict__ bih2, const float* __restrict__ bhh2,
                            float* __restrict__ ws) {
    int e = blockIdx.x * 256 + threadIdx.x;
    if (e >= PACK_TOT) return;
    _Float16* wh = (_Float16*)ws;
    float* bptr = (float*)(wh + BSUM_HALF_OFF);
    auto gscale = [](int q) -> float {
        int gt = q >> 6;                       // 0=i,1=f,2=g,3=o
        return (gt == 2) ? (-2.0f * L2E) : -L2E;
    };
    if (e < PK2_OFF) {
        int j = e & 7, lane = (e >> 3) & 63, nt = (e >> 9) & 15, c = e >> 13;
        int k = c * 32 + 4 * (lane >> 4) + (j & 3) + 16 * (j >> 2);
        int q = nt * 16 + (lane & 15);
        float v = 0.0f;
        if (k < 64)      v = Whh1[q * 64 + k];
        else if (k < 73) v = Wih1[q * 9 + (k - 64)];
        wh[e] = (_Float16)(v * gscale(q));
    } else if (e < PACK_W_TOT) {
        int e2 = e - PK2_OFF;
        int j = e2 & 7, lane = (e2 >> 3) & 63, nt = (e2 >> 9) & 15, c = e2 >> 13;
        int k = c * 32 + 4 * (lane >> 4) + (j & 3) + 16 * (j >> 2);
        int q = nt * 16 + (lane & 15);
        float v = (k < 64) ? Wih2[q * 64 + k] : Whh2[q * 64 + (k - 64)];
        wh[e] = (_Float16)(v * gscale(q));
    } else if (e < PACK_W_TOT + 256) {
        int q = e - PACK_W_TOT;
        bptr[q] = (bih1[q] + bhh1[q]) * gscale(q);
    } else {
        int q = e - PACK_W_TOT - 256;
        bptr[256 + q] = (bih2[q] + bhh2[q]) * gscale(q);
    }
}

// ---------------- main sequential LSTM ----------------
__global__ __launch_bounds__(256, 2) void lstm_mfma(
    const float* __restrict__ x,
    const float* __restrict__ ws_f,
    const float* __restrict__ Wout,
    const float* __restrict__ bout,
    float* __restrict__ out)
{
    const int tid  = threadIdx.x;
    const int lane = tid & 63;
    const int w    = __builtin_amdgcn_readfirstlane(tid >> 6);   // 0..3
    const int l15  = lane & 15;
    const int l4   = lane >> 4;

    const _Float16* wh  = (const _Float16*)ws_f;
    const _Float16* pk1 = wh + PK1_OFF;
    const _Float16* pk2 = wh + PK2_OFF;
    const float* bsum   = (const float*)(wh + BSUM_HALF_OFF);

    __shared__ _Float16 h1s[2][16][72];
    __shared__ _Float16 h2s[2][16][72];
    __shared__ _Float16 xwin[2][8][4][16][4];   // [buf][step&7][quad][batch][4]

    for (int i = tid; i < 2 * 16 * 72; i += 256) {
        (&h1s[0][0][0])[i] = (_Float16)0.0f;
        (&h2s[0][0][0])[i] = (_Float16)0.0f;
    }
    for (int i = tid; i < 2 * 8 * 4 * 16 * 4; i += 256)
        (&xwin[0][0][0][0][0])[i] = (_Float16)0.0f;

    const int bbase = blockIdx.x * 16;

    // ---- x loader (R8): thread handles batch b_=tid&15, entries z_ and z_+16
    const int b_ = tid & 15, z_ = tid >> 4;
    const int s0_ = (z_ * 11) >> 5, q0_ = z_ - 3 * s0_;
    const bool act1 = (z_ < 8);
    const int pz1 = z_ + 16;
    const int s1_ = (pz1 * 11) >> 5, q1_ = pz1 - 3 * s1_;
    const float* xbL = x + (long)(bbase + b_) * (T_STEPS * IN_DIM);

    f4u pfA = {0.f, 0.f, 0.f, 0.f}, pfB = {0.f, 0.f, 0.f, 0.f};
    auto fetch_x = [&](int wb) {
        int t0 = wb + s0_; if (t0 > T_STEPS - 1) t0 = T_STEPS - 1;
        const float* p0 = xbL + t0 * IN_DIM + 4 * q0_;
        if (q0_ < 2) pfA = *(const f4u*)p0; else pfA[0] = p0[0];
        if (act1) {
            int t1 = wb + s1_; if (t1 > T_STEPS - 1) t1 = T_STEPS - 1;
            const float* p1 = xbL + t1 * IN_DIM + 4 * q1_;
            if (q1_ < 2) pfB = *(const f4u*)p1; else pfB[0] = p1[0];
        }
    };
    auto store_x = [&](int buf) {
        f4u A = pfA, B = pfB;
        if (q0_ == 2) { A[1] = 0.f; A[2] = 0.f; A[3] = 0.f; }
        half4v hv;
        hv[0] = (_Float16)A[0]; hv[1] = (_Float16)A[1];
        hv[2] = (_Float16)A[2]; hv[3] = (_Float16)A[3];
        *(half4v*)&xwin[buf][s0_][q0_][b_][0] = hv;
        if (act1) {
            if (q1_ == 2) { B[1] = 0.f; B[2] = 0.f; B[3] = 0.f; }
            half4v hw;
            hw[0] = (_Float16)B[0]; hw[1] = (_Float16)B[1];
            hw[2] = (_Float16)B[2]; hw[3] = (_Float16)B[3];
            *(half4v*)&xwin[buf][s1_][q1_][b_][0] = hw;
        }
    };
    auto read_ax = [&](int tt) -> half8 {
        half4v xq = *(const half4v*)&xwin[(tt >> 3) & 1][tt & 7][l4][l15][0];
        return __builtin_shufflevector(xq, xq, 0, 1, 2, 3, 0, 1, 2, 3);
    };

    // ---- weight B-fragments: 28 x half8, loop-pinned (1 pin/iter)
    half8 bw1_00, bw1_01, bw1_02, bw1_03;
    half8 bw1_10, bw1_11, bw1_12, bw1_13;
    half8 bw1_20, bw1_21, bw1_22, bw1_23;
    half8 bw2_00, bw2_01, bw2_02, bw2_03;
    half8 bw2_10, bw2_11, bw2_12, bw2_13;
    half8 bw2_20, bw2_21, bw2_22, bw2_23;
    half8 bw2_30, bw2_31, bw2_32, bw2_33;
    {
        #define LD1(c,g) *(const half8*)(pk1 + (((c * 16) + (w + 4 * g)) * 64 + lane) * 8)
        #define LD2(c,g) *(const half8*)(pk2 + (((c * 16) + (w + 4 * g)) * 64 + lane) * 8)
        bw1_00 = LD1(0,0); bw1_01 = LD1(0,1); bw1_02 = LD1(0,2); bw1_03 = LD1(0,3);
        bw1_10 = LD1(1,0); bw1_11 = LD1(1,1); bw1_12 = LD1(1,2); bw1_13 = LD1(1,3);
        bw1_20 = LD1(2,0); bw1_21 = LD1(2,1); bw1_22 = LD1(2,2); bw1_23 = LD1(2,3);
        bw2_00 = LD2(0,0); bw2_01 = LD2(0,1); bw2_02 = LD2(0,2); bw2_03 = LD2(0,3);
        bw2_10 = LD2(1,0); bw2_11 = LD2(1,1); bw2_12 = LD2(1,2); bw2_13 = LD2(1,3);
        bw2_20 = LD2(2,0); bw2_21 = LD2(2,1); bw2_22 = LD2(2,2); bw2_23 = LD2(2,3);
        bw2_30 = LD2(3,0); bw2_31 = LD2(3,1); bw2_32 = LD2(3,2); bw2_33 = LD2(3,3);
        #undef LD1
        #undef LD2
    }

    float bias1[4], bias2[4];
    #pragma unroll
    for (int g = 0; g < 4; ++g) {
        bias1[g] = bsum[(w + 4 * g) * 16 + l15];
        bias2[g] = bsum[256 + (w + 4 * g) * 16 + l15];
    }

    const int hpos = ((w >> 1) << 5) + 8 * (l15 >> 2) + (l15 & 3) + ((w & 1) << 2);

    f32x4 c1 = {0.f, 0.f, 0.f, 0.f};
    f32x4 c2 = {0.f, 0.f, 0.f, 0.f};

    // ---- packed-f32 cell pair (R11)
    auto cell_pair = [&](f32x2 Gi, f32x2 Gf, f32x2 Gg, f32x2 Go,
                         f32x2& cs, _Float16* hb, int rb) {
        const f32x2 one = {1.0f, 1.0f};
        f32x2 ei, ef, eg, eo;
        ei.x = __builtin_amdgcn_exp2f(Gi.x); ei.y = __builtin_amdgcn_exp2f(Gi.y);
        ef.x = __builtin_amdgcn_exp2f(Gf.x); ef.y = __builtin_amdgcn_exp2f(Gf.y);
        eg.x = __builtin_amdgcn_exp2f(Gg.x); eg.y = __builtin_amdgcn_exp2f(Gg.y);
        eo.x = __builtin_amdgcn_exp2f(Go.x); eo.y = __builtin_amdgcn_exp2f(Go.y);
        f32x2 ai = ei + one, af = ef + one, ag = eg + one;
        f32x2 gm = one - eg;
        f32x2 pp = ai * ag;
        f32x2 num = gm * af + cs * pp;
        f32x2 den = af * pp;
        float s  = den.x * den.y;
        float rs = __builtin_amdgcn_rcpf(s);
        f32x2 inv = {rs * den.y, rs * den.x};
        f32x2 cc = num * inv;
        cs = cc;
        f32x2 z = cc * (f32x2){TWOL2E, TWOL2E};
        int zx = __float_as_int(z.x), zy = __float_as_int(z.y);
        f32x2 ec;
        ec.x = __builtin_amdgcn_exp2f(__int_as_float(zx | (int)0x80000000));
        ec.y = __builtin_amdgcn_exp2f(__int_as_float(zy | (int)0x80000000));
        f32x2 tm = one - ec;
        f32x2 d2 = (eo + one) * (ec + one);
        float t  = d2.x * d2.y;
        float rt = __builtin_amdgcn_rcpf(t);
        f32x2 jnv = {rt * d2.y, rt * d2.x};
        f32x2 hsv;
        hsv.x = __int_as_float(__float_as_int(tm.x) ^ (zx & (int)0x80000000));
        hsv.y = __int_as_float(__float_as_int(tm.y) ^ (zy & (int)0x80000000));
        f32x2 hv = hsv * jnv;
        hb[(4 * l4 + rb)     * 72 + hpos] = (_Float16)hv.x;
        hb[(4 * l4 + rb + 1) * 72 + hpos] = (_Float16)hv.y;
    };

    auto cell_update = [&](f32x4* G, f32x4& cs, _Float16* hb) {
        f32x2 csL = {cs[0], cs[1]}, csH = {cs[2], cs[3]};
        cell_pair((f32x2){G[0][0], G[0][1]}, (f32x2){G[1][0], G[1][1]},
                  (f32x2){G[2][0], G[2][1]}, (f32x2){G[3][0], G[3][1]},
                  csL, hb, 0);
        cell_pair((f32x2){G[0][2], G[0][3]}, (f32x2){G[1][2], G[1][3]},
                  (f32x2){G[2][2], G[2][3]}, (f32x2){G[3][2], G[3][3]},
                  csH, hb, 2);
        cs[0] = csL.x; cs[1] = csL.y; cs[2] = csH.x; cs[3] = csH.y;
    };

    #define PIN_ALL() do {                                                      \
        asm volatile("" :                                                       \
            "+v"(bw1_00), "+v"(bw1_01), "+v"(bw1_02), "+v"(bw1_03),             \
            "+v"(bw1_10), "+v"(bw1_11), "+v"(bw1_12), "+v"(bw1_13),             \
            "+v"(bw1_20), "+v"(bw1_21), "+v"(bw1_22), "+v"(bw1_23));            \
        asm volatile("" :                                                       \
            "+v"(bw2_00), "+v"(bw2_01), "+v"(bw2_02), "+v"(bw2_03),             \
            "+v"(bw2_10), "+v"(bw2_11), "+v"(bw2_12), "+v"(bw2_13),             \
            "+v"(bw2_20), "+v"(bw2_21), "+v"(bw2_22), "+v"(bw2_23),             \
            "+v"(bw2_30), "+v"(bw2_31), "+v"(bw2_32), "+v"(bw2_33),             \
            "+v"(bias1[0]), "+v"(bias1[1]), "+v"(bias1[2]), "+v"(bias1[3]),     \
            "+v"(bias2[0]), "+v"(bias2[1]), "+v"(bias2[2]), "+v"(bias2[3]));    \
    } while (0)

    // ---- preloop: fill x window 0, prefetch window 1, init C = gates1(0)
    fetch_x(0);
    __syncthreads();              // LDS zeros committed before store_x
    store_x(0);                   // buf0 = x(0..7)
    fetch_x(8);                   // regs = x(8..15), stored at t=0
    __syncthreads();              // window 0 + zero h state visible

    f32x4 C[4];
    {
        half8 ax0 = read_ax(0);
        #pragma unroll
        for (int g = 0; g < 4; ++g) C[g] = (f32x4){bias1[g], bias1[g], bias1[g], bias1[g]};
        C[0] = __builtin_amdgcn_mfma_f32_16x16x32_f16(ax0, bw1_20, C[0], 0, 0, 0);
        C[1] = __builtin_amdgcn_mfma_f32_16x16x32_f16(ax0, bw1_21, C[1], 0, 0, 0);
        C[2] = __builtin_amdgcn_mfma_f32_16x16x32_f16(ax0, bw1_22, C[2], 0, 0, 0);
        C[3] = __builtin_amdgcn_mfma_f32_16x16x32_f16(ax0, bw1_23, C[3], 0, 0, 0);
    }

    for (int t = 0; t < T_STEPS; t += 2) {
        PIN_ALL();                            // ONE pin per iteration

        // ======== step t (even): writes parity 1, reads h2 parity 0
        half8 axA = read_ax(t + 1);           // pre-barrier (xwin long visible)
        cell_update(C, c1, &h1s[1][0][0]);    // h1(t)
        if ((t & 7) == 0) {
            store_x(((t >> 3) + 1) & 1);
            fetch_x(t + 16);
        }
        __syncthreads();                      // B1: h1(t) visible

        half8 a10  = *(const half8*)&h1s[1][l15][ 0 + 8 * l4];
        half8 a11  = *(const half8*)&h1s[1][l15][32 + 8 * l4];
        half8 a2h0 = *(const half8*)&h2s[0][l15][ 0 + 8 * l4];
        half8 a2h1 = *(const half8*)&h2s[0][l15][32 + 8 * l4];

        f32x4 D[4];
        #pragma unroll
        for (int g = 0; g < 4; ++g) D[g] = (f32x4){bias2[g], bias2[g], bias2[g], bias2[g]};
        D[0] = __builtin_amdgcn_mfma_f32_16x16x32_f16(a10,  bw2_00, D[0], 0, 0, 0);
        D[1] = __builtin_amdgcn_mfma_f32_16x16x32_f16(a10,  bw2_01, D[1], 0, 0, 0);
        D[2] = __builtin_amdgcn_mfma_f32_16x16x32_f16(a10,  bw2_02, D[2], 0, 0, 0);
        D[3] = __builtin_amdgcn_mfma_f32_16x16x32_f16(a10,  bw2_03, D[3], 0, 0, 0);
        D[0] = __builtin_amdgcn_mfma_f32_16x16x32_f16(a11,  bw2_10, D[0], 0, 0, 0);
        D[1] = __builtin_amdgcn_mfma_f32_16x16x32_f16(a11,  bw2_11, D[1], 0, 0, 0);
        D[2] = __builtin_amdgcn_mfma_f32_16x16x32_f16(a11,  bw2_12, D[2], 0, 0, 0);
        D[3] = __builtin_amdgcn_mfma_f32_16x16x32_f16(a11,  bw2_13, D[3], 0, 0, 0);
        D[0] = __builtin_amdgcn_mfma_f32_16x16x32_f16(a2h0, bw2_20, D[0], 0, 0, 0);
        D[1] = __builtin_amdgcn_mfma_f32_16x16x32_f16(a2h0, bw2_21, D[1], 0, 0, 0);
        D[2] = __builtin_amdgcn_mfma_f32_16x16x32_f16(a2h0, bw2_22, D[2], 0, 0, 0);
        D[3] = __builtin_amdgcn_mfma_f32_16x16x32_f16(a2h0, bw2_23, D[3], 0, 0, 0);
        D[0] = __builtin_amdgcn_mfma_f32_16x16x32_f16(a2h1, bw2_30, D[0], 0, 0, 0);
        D[1] = __builtin_amdgcn_mfma_f32_16x16x32_f16(a2h1, bw2_31, D[1], 0, 0, 0);
        D[2] = __builtin_amdgcn_mfma_f32_16x16x32_f16(a2h1, bw2_32, D[2], 0, 0, 0);
        D[3] = __builtin_amdgcn_mfma_f32_16x16x32_f16(a2h1, bw2_33, D[3], 0, 0, 0);

        f32x4 CB[4];
        #pragma unroll
        for (int g = 0; g < 4; ++g) CB[g] = (f32x4){bias1[g], bias1[g], bias1[g], bias1[g]};
        CB[0] = __builtin_amdgcn_mfma_f32_16x16x32_f16(a10, bw1_00, CB[0], 0, 0, 0);
        CB[1] = __builtin_amdgcn_mfma_f32_16x16x32_f16(a10, bw1_01, CB[1], 0, 0, 0);
        CB[2] = __builtin_amdgcn_mfma_f32_16x16x32_f16(a10, bw1_02, CB[2], 0, 0, 0);
        CB[3] = __builtin_amdgcn_mfma_f32_16x16x32_f16(a10, bw1_03, CB[3], 0, 0, 0);
        CB[0] = __builtin_amdgcn_mfma_f32_16x16x32_f16(a11, bw1_10, CB[0], 0, 0, 0);
        CB[1] = __builtin_amdgcn_mfma_f32_16x16x32_f16(a11, bw1_11, CB[1], 0, 0, 0);
        CB[2] = __builtin_amdgcn_mfma_f32_16x16x32_f16(a11, bw1_12, CB[2], 0, 0, 0);
        CB[3] = __builtin_amdgcn_mfma_f32_16x16x32_f16(a11, bw1_13, CB[3], 0, 0, 0);
        CB[0] = __builtin_amdgcn_mfma_f32_16x16x32_f16(axA, bw1_20, CB[0], 0, 0, 0);
        CB[1] = __builtin_amdgcn_mfma_f32_16x16x32_f16(axA, bw1_21, CB[1], 0, 0, 0);
        CB[2] = __builtin_amdgcn_mfma_f32_16x16x32_f16(axA, bw1_22, CB[2], 0, 0, 0);
        CB[3] = __builtin_amdgcn_mfma_f32_16x16x32_f16(axA, bw1_23, CB[3], 0, 0, 0);

        // merged 8-cell trans region: L2(t) + L1(t+1), interleavable chains
        cell_update(D,  c2, &h2s[1][0][0]);   // h2(t)
        cell_update(CB, c1, &h1s[0][0][0]);   // h1(t+1)

        // ======== step t+1 (odd): writes parity 0, reads h2 parity 1
        half8 axB = read_ax(t + 2);           // pre-barrier
        __syncthreads();                      // B2: h1(t+1) visible

        half8 b10  = *(const half8*)&h1s[0][l15][ 0 + 8 * l4];
        half8 b11  = *(const half8*)&h1s[0][l15][32 + 8 * l4];
        half8 b2h0 = *(const half8*)&h2s[1][l15][ 0 + 8 * l4];
        half8 b2h1 = *(const half8*)&h2s[1][l15][32 + 8 * l4];

        f32x4 E[4];
        #pragma unroll
        for (int g = 0; g < 4; ++g) E[g] = (f32x4){bias2[g], bias2[g], bias2[g], bias2[g]};
        E[0] = __builtin_amdgcn_mfma_f32_16x16x32_f16(b10,  bw2_00, E[0], 0, 0, 0);
        E[1] = __builtin_amdgcn_mfma_f32_16x16x32_f16(b10,  bw2_01, E[1], 0, 0, 0);
        E[2] = __builtin_amdgcn_mfma_f32_16x16x32_f16(b10,  bw2_02, E[2], 0, 0, 0);
        E[3] = __builtin_amdgcn_mfma_f32_16x16x32_f16(b10,  bw2_03, E[3], 0, 0, 0);
        E[0] = __builtin_amdgcn_mfma_f32_16x16x32_f16(b11,  bw2_10, E[0], 0, 0, 0);
        E[1] = __builtin_amdgcn_mfma_f32_16x16x32_f16(b11,  bw2_11, E[1], 0, 0, 0);
        E[2] = __builtin_amdgcn_mfma_f32_16x16x32_f16(b11,  bw2_12, E[2], 0, 0, 0);
        E[3] = __builtin_amdgcn_mfma_f32_16x16x32_f16(b11,  bw2_13, E[3], 0, 0, 0);
        E[0] = __builtin_amdgcn_mfma_f32_16x16x32_f16(b2h0, bw2_20, E[0], 0, 0, 0);
        E[1] = __builtin_amdgcn_mfma_f32_16x16x32_f16(b2h0, bw2_21, E[1], 0, 0, 0);
        E[2] = __builtin_amdgcn_mfma_f32_16x16x32_f16(b2h0, bw2_22, E[2], 0, 0, 0);
        E[3] = __builtin_amdgcn_mfma_f32_16x16x32_f16(b2h0, bw2_23, E[3], 0, 0, 0);
        E[0] = __builtin_amdgcn_mfma_f32_16x16x32_f16(b2h1, bw2_30, E[0], 0, 0, 0);
        E[1] = __builtin_amdgcn_mfma_f32_16x16x32_f16(b2h1, bw2_31, E[1], 0, 0, 0);
        E[2] = __builtin_amdgcn_mfma_f32_16x16x32_f16(b2h1, bw2_32, E[2], 0, 0, 0);
        E[3] = __builtin_amdgcn_mfma_f32_16x16x32_f16(b2h1, bw2_33, E[3], 0, 0, 0);

        #pragma unroll
        for (int g = 0; g < 4; ++g) C[g] = (f32x4){bias1[g], bias1[g], bias1[g], bias1[g]};
        C[0] = __builtin_amdgcn_mfma_f32_16x16x32_f16(b10, bw1_00, C[0], 0, 0, 0);
        C[1] = __builtin_amdgcn_mfma_f32_16x16x32_f16(b10, bw1_01, C[1], 0, 0, 0);
        C[2] = __builtin_amdgcn_mfma_f32_16x16x32_f16(b10, bw1_02, C[2], 0, 0, 0);
        C[3] = __builtin_amdgcn_mfma_f32_16x16x32_f16(b10, bw1_03, C[3], 0, 0, 0);
        C[0] = __builtin_amdgcn_mfma_f32_16x16x32_f16(b11, bw1_10, C[0], 0, 0, 0);
        C[1] = __builtin_amdgcn_mfma_f32_16x16x32_f16(b11, bw1_11, C[1], 0, 0, 0);
        C[2] = __builtin_amdgcn_mfma_f32_16x16x32_f16(b11, bw1_12, C[2], 0, 0, 0);
        C[3] = __builtin_amdgcn_mfma_f32_16x16x32_f16(b11, bw1_13, C[3], 0, 0, 0);
        C[0] = __builtin_amdgcn_mfma_f32_16x16x32_f16(axB, bw1_20, C[0], 0, 0, 0);
        C[1] = __builtin_amdgcn_mfma_f32_16x16x32_f16(axB, bw1_21, C[1], 0, 0, 0);
        C[2] = __builtin_amdgcn_mfma_f32_16x16x32_f16(axB, bw1_22, C[2], 0, 0, 0);
        C[3] = __builtin_amdgcn_mfma_f32_16x16x32_f16(axB, bw1_23, C[3], 0, 0, 0);

        cell_update(E, c2, &h2s[0][0][0]);    // h2(t+1); h1(t+2) at next iter top
    }
    __syncthreads();   // final h2 writes visible

    // ---- output head: h2(199) in h2s[0] (perm-stored)
    if (tid < 48) {
        int bl = tid / 3, o = tid - bl * 3;
        float acc = bout[o];
        #pragma unroll 8
        for (int pos = 0; pos < HDIM; ++pos) {
            int sub = pos & 31;
            int j = (pos >> 5) * 32 + (((sub >> 2) & 1) << 4) + ((sub >> 3) << 2) + (sub & 3);
            acc = __builtin_fmaf(Wout[o * 64 + j], (float)h2s[0][bl][pos], acc);
        }
        out[(bbase + bl) * 3 + o] = acc;
    }
    #undef PIN_ALL
}

extern "C" void kernel_launch(void* const* d_in, const int* in_sizes, int n_in,
                              void* d_out, int out_size, void* d_ws, size_t ws_size,
                              hipStream_t stream) {
    const float* x     = (const float*)d_in[0];
    const float* Wih1  = (const float*)d_in[1];
    const float* Whh1  = (const float*)d_in[2];
    const float* bih1  = (const float*)d_in[3];
    const float* bhh1  = (const float*)d_in[4];
    const float* Wih2  = (const float*)d_in[5];
    const float* Whh2  = (const float*)d_in[6];
    const float* bih2  = (const float*)d_in[7];
    const float* bhh2  = (const float*)d_in[8];
    const float* Wout  = (const float*)d_in[9];
    const float* bout  = (const float*)d_in[10];
    float* ws  = (float*)d_ws;
    float* out = (float*)d_out;

    pack_kernel<<<(PACK_TOT + 255) / 256, 256, 0, stream>>>(
        Wih1, Whh1, bih1, bhh1, Wih2, Whh2, bih2, bhh2, ws);

    lstm_mfma<<<B_TOT / 16, 256, 0, stream>>>(x, ws, Wout, bout, out);
}